// Round 1
// baseline (150.009 us; speedup 1.0000x reference)
//
#include <hip/hip_runtime.h>
#include <hip/hip_bf16.h>

// EmbeddingDropout: out[b,s,:] = weight[x[b,s],:] * mask[x[b,s]]
// B*S = 16384 tokens, D = 512. One float4 per thread, fully coalesced.
// D/4 = 128 float4 per row.

__global__ __launch_bounds__(256) void EmbeddingDropout_70592082477707_kernel(
    const int* __restrict__ x,        // [B*S] token ids (int32)
    const float4* __restrict__ w,     // [V, D/4] weight as float4
    const float* __restrict__ mask,   // [V] per-row dropout scale
    float4* __restrict__ out,         // [B*S, D/4]
    int n_vec4)                       // B*S * D/4
{
    int i = blockIdx.x * blockDim.x + threadIdx.x;
    if (i >= n_vec4) return;

    int token = i >> 7;          // D/4 = 128
    int col   = i & 127;

    int row = x[token];
    float m = mask[row];

    float4 v = w[(size_t)row * 128 + col];
    v.x *= m; v.y *= m; v.z *= m; v.w *= m;
    out[i] = v;
}

extern "C" void kernel_launch(void* const* d_in, const int* in_sizes, int n_in,
                              void* d_out, int out_size, void* d_ws, size_t ws_size,
                              hipStream_t stream) {
    const int*    x    = (const int*)d_in[0];      // [B*S] int32
    const float4* w    = (const float4*)d_in[1];   // [V, 512] fp32 -> float4
    const float*  mask = (const float*)d_in[2];    // [V] fp32
    float4*       out  = (float4*)d_out;           // [B*S, 512] fp32 -> float4

    int n_vec4 = out_size / 4;                     // 8*2048*512/4 = 2,097,152
    int block = 256;
    int grid = (n_vec4 + block - 1) / block;       // 8192 blocks

    EmbeddingDropout_70592082477707_kernel<<<grid, block, 0, stream>>>(
        x, w, mask, out, n_vec4);
}